// Round 14
// baseline (792.709 us; speedup 1.0000x reference)
//
#include <hip/hip_runtime.h>
#include <hip/hip_bf16.h>

#define BATCH 64
#define CDIM  256
#define MHW   196
#define MP    224      // padded K for covariance (multiple of 32)
#define EDIM  512
#define CC    65536    // CDIM*CDIM
#define NTRI  10       // upper-triangle 64x64 tiles of a 256x256 matrix
#define NMM   (BATCH * NTRI)   // 640 chain blocks
#define NSTEP 5        // arrive-gated steps (cov, Y1, T2, Y2+Z2, T3)

typedef __attribute__((ext_vector_type(8))) short short8_t;   // 8 x bf16 MFMA frag
typedef __attribute__((ext_vector_type(4))) float f32x4;
typedef __attribute__((ext_vector_type(4))) unsigned int u32x4;

static __device__ __forceinline__ short f2bf(float f) {
    __hip_bfloat16 h = __float2bfloat16(f);
    return (short)__builtin_bit_cast(unsigned short, h);
}

// ---------------------------------------------------------------------------
// Kernel 1: per-(b,c) row centering + bf16 cast (pad to MP) + rowsq.
// XCD swizzle: blockIdx = r4*64 + b (round-9 win). Block 0 zeroes ALL the
// chain's 320 flag counters via a strided loop (round-13 bug: a plain
// tid<320 test with 256 threads left flags 256..319 stale -> race).
// ---------------------------------------------------------------------------
__global__ __launch_bounds__(256) void k_center(const float* __restrict__ feat,
                                                __hip_bfloat16* __restrict__ xcb,
                                                float* __restrict__ rowsq,
                                                unsigned int* __restrict__ cnt)
{
    if (blockIdx.x == 0) {
        for (int i = threadIdx.x; i < BATCH * NSTEP; i += 256) cnt[i] = 0;
    }
    const int b  = blockIdx.x & 63;
    const int r4 = blockIdx.x >> 6;
    const int row = b * 256 + r4 * 4 + (threadIdx.x >> 6);
    const int l = threadIdx.x & 63;
    const float* src = feat + (size_t)row * MHW;
    float v0 = src[l];
    float v1 = src[l + 64];
    float v2 = src[l + 128];
    float v3 = (l + 192 < MHW) ? src[l + 192] : 0.0f;
    float s = v0 + v1 + v2 + v3;
    #pragma unroll
    for (int o = 32; o >= 1; o >>= 1) s += __shfl_xor(s, o, 64);
    const float mean = s * (1.0f / MHW);
    v0 -= mean; v1 -= mean; v2 -= mean;
    v3 = (l + 192 < MHW) ? (v3 - mean) : 0.0f;
    float sq = v0*v0 + v1*v1 + v2*v2 + v3*v3;
    #pragma unroll
    for (int o = 32; o >= 1; o >>= 1) sq += __shfl_xor(sq, o, 64);
    if (l == 0) rowsq[row] = sq;
    __hip_bfloat16* dst = xcb + (size_t)row * MP;
    dst[l]       = __float2bfloat16(v0);
    dst[l + 64]  = __float2bfloat16(v1);
    dst[l + 128] = __float2bfloat16(v2);
    if (l + 192 < MP) dst[l + 192] = __float2bfloat16(v3);   // includes zero pad
}

// ---------------------------------------------------------------------------
// mm_body: round-9 k_mm inner loop verbatim, as a device function.
// out = a*(A@B) + beta*D + gamma*I for 64x64 tile (ti,tj) of batch b.
// B stored exactly symmetric (mirror writes) so row-reads give B^T columns.
// ---------------------------------------------------------------------------
template<int KT, bool NORM>
static __device__ __forceinline__ void mm_body(
    const __hip_bfloat16* __restrict__ A, const __hip_bfloat16* __restrict__ Bm,
    const __hip_bfloat16* __restrict__ D, __hip_bfloat16* __restrict__ out,
    const float* __restrict__ alpha_rowsq, float alpha_c, float beta, float gamma,
    float* __restrict__ nrm, int b, int ti, int tj, int t,
    __hip_bfloat16 (*As)[72], __hip_bfloat16 (*Bs)[72],
    float* red, float* s_alpha)
{
    const int tid = threadIdx.x;
    const int wv = tid >> 6, l = tid & 63;
    const int wr = wv >> 1, wc = wv & 1;
    const int lr = l & 15,  lg = l >> 4;

    if (alpha_rowsq) {
        float v = alpha_rowsq[b * 256 + tid];
        #pragma unroll
        for (int o = 32; o >= 1; o >>= 1) v += __shfl_xor(v, o, 64);
        if (l == 0) red[wv] = v;
        __syncthreads();
        if (tid == 0) *s_alpha = alpha_c / (red[0] + red[1] + red[2] + red[3]);
    } else if (tid == 0) {
        *s_alpha = alpha_c;
    }

    const __hip_bfloat16* Ab = A  + (size_t)b * (CDIM * KT) + (size_t)ti * 64 * KT;
    const __hip_bfloat16* Bb = Bm + (size_t)b * (CDIM * KT) + (size_t)tj * 64 * KT;

    f32x4 acc[2][2];
    #pragma unroll
    for (int i = 0; i < 2; i++)
        #pragma unroll
        for (int j = 0; j < 2; j++)
            #pragma unroll
            for (int r = 0; r < 4; r++) acc[i][j][r] = 0.0f;

    #pragma unroll
    for (int k0 = 0; k0 < KT; k0 += 64) {
        const int kw   = (KT - k0 >= 64) ? 64 : (KT - k0);   // 64 or 32
        const int segs = kw >> 3;                            // 8 or 4
        __syncthreads();
        for (int u = tid; u < 64 * segs; u += 256) {
            const int row = u / segs;
            const int seg = u - row * segs;
            *reinterpret_cast<u32x4*>(&As[row][seg * 8]) =
                *reinterpret_cast<const u32x4*>(Ab + (size_t)row * KT + k0 + seg * 8);
            *reinterpret_cast<u32x4*>(&Bs[row][seg * 8]) =
                *reinterpret_cast<const u32x4*>(Bb + (size_t)row * KT + k0 + seg * 8);
        }
        __syncthreads();
        const int nks = kw >> 5;   // 2 or 1
        for (int ks = 0; ks < nks; ks++) {
            short8_t af[2], bfr[2];
            #pragma unroll
            for (int i = 0; i < 2; i++)
                af[i] = *reinterpret_cast<const short8_t*>(&As[wr * 32 + i * 16 + lr][ks * 32 + lg * 8]);
            #pragma unroll
            for (int j = 0; j < 2; j++)
                bfr[j] = *reinterpret_cast<const short8_t*>(&Bs[wc * 32 + j * 16 + lr][ks * 32 + lg * 8]);
            #pragma unroll
            for (int i = 0; i < 2; i++)
                #pragma unroll
                for (int j = 0; j < 2; j++)
                    acc[i][j] = __builtin_amdgcn_mfma_f32_16x16x32_bf16(af[i], bfr[j], acc[i][j], 0, 0, 0);
        }
    }

    const float a = *s_alpha;
    __hip_bfloat16* ob = out + (size_t)b * CC;
    const __hip_bfloat16* Db = D ? (D + (size_t)b * CC) : nullptr;
    float ns = 0.0f;
    #pragma unroll
    for (int i = 0; i < 2; i++) {
        #pragma unroll
        for (int j = 0; j < 2; j++) {
            #pragma unroll
            for (int r = 0; r < 4; r++) {
                const int grow = ti * 64 + wr * 32 + i * 16 + lg * 4 + r;
                const int gcol = tj * 64 + wc * 32 + j * 16 + lr;
                float v = a * acc[i][j][r];
                if (Db) v += beta * __bfloat162float(Db[grow * 256 + gcol]);
                if (grow == gcol) v += gamma;
                const __hip_bfloat16 hv = __float2bfloat16(v);
                ob[grow * 256 + gcol] = hv;
                if (ti != tj) ob[gcol * 256 + grow] = hv;   // exact-symmetry mirror
                if (NORM) {
                    const float fv = __bfloat162float(hv);
                    ns += ((ti != tj) ? 2.0f : 1.0f) * fv * fv;
                }
            }
        }
    }
    if constexpr (NORM) {
        #pragma unroll
        for (int o = 32; o >= 1; o >>= 1) ns += __shfl_xor(ns, o, 64);
        __syncthreads();
        if (l == 0) red[wv] = ns;
        __syncthreads();
        if (tid == 0) nrm[b * NTRI + t] = red[0] + red[1] + red[2] + red[3];
    }
}

// ---------------------------------------------------------------------------
// Per-batch flag sync (NOT grid.sync — round-5 lesson). Release: fence all
// stores, then one device-scope atomicAdd. Acquire: poll relaxed, then fence.
// Only the 10 blocks of one batch converge -> batches pipeline independently.
// ---------------------------------------------------------------------------
static __device__ __forceinline__ void arrive(unsigned int* c)
{
    __threadfence();
    __syncthreads();
    if (threadIdx.x == 0)
        __hip_atomic_fetch_add(c, 1u, __ATOMIC_RELAXED, __HIP_MEMORY_SCOPE_AGENT);
}
static __device__ __forceinline__ void waitall(unsigned int* c)
{
    if (threadIdx.x == 0)
        while (__hip_atomic_load(c, __ATOMIC_RELAXED, __HIP_MEMORY_SCOPE_AGENT) < NTRI)
            __builtin_amdgcn_s_sleep(2);
    __syncthreads();
    __threadfence();
}

// ---------------------------------------------------------------------------
// k_chain: the full NS chain in ONE launch. Block (b,t) = tile t of batch b;
// per-batch flags between steps. (256,4): VGPR<=128 -> >=4 blocks/CU ->
// capacity 1024 >= 640, all blocks co-resident (deadlock-free).
// Step math byte-identical to round 9's six k_mm launches.
// ---------------------------------------------------------------------------
__global__ __launch_bounds__(256, 4) void k_chain(
    const __hip_bfloat16* __restrict__ xcb, const float* __restrict__ rowsq,
    __hip_bfloat16* __restrict__ M0, __hip_bfloat16* __restrict__ M1,
    __hip_bfloat16* __restrict__ M2, __hip_bfloat16* __restrict__ M3,
    __hip_bfloat16* __restrict__ M4, float* __restrict__ nrmp,
    unsigned int* __restrict__ cnt)
{
    __shared__ __hip_bfloat16 As[64][72];
    __shared__ __hip_bfloat16 Bs[64][72];
    __shared__ float red[4];
    __shared__ float s_alpha;

    const int b = blockIdx.x & 63;
    const int t = blockIdx.x >> 6;
    int ti, tj;
    if (t < 4)      { ti = 0; tj = t; }
    else if (t < 7) { ti = 1; tj = t - 3; }
    else if (t < 9) { ti = 2; tj = t - 5; }
    else            { ti = 3; tj = 3; }
    unsigned int* cb = cnt + b * NSTEP;

    // y  = (1/tr) * xc @ xc^T                          -> M0
    mm_body<MP, false>(xcb, xcb, nullptr, M0, rowsq, 1.0f, 0.0f, 0.0f, nullptr,
                       b, ti, tj, t, As, Bs, red, &s_alpha);
    arrive(cb + 0); waitall(cb + 0);
    // Y1 = -0.5*y@y + 1.5*y                            -> M1
    mm_body<256, false>(M0, M0, M0, M1, nullptr, -0.5f, 1.5f, 0.0f, nullptr,
                        b, ti, tj, t, As, Bs, red, &s_alpha);
    arrive(cb + 1); waitall(cb + 1);
    // T2 = 0.5*y@Y1 - 1.5*Y1 + 3I                      -> M2
    mm_body<256, false>(M0, M1, M1, M2, nullptr, 0.5f, -1.5f, 3.0f, nullptr,
                        b, ti, tj, t, As, Bs, red, &s_alpha);
    arrive(cb + 2); waitall(cb + 2);
    // Y2 = 0.5*Y1@T2 -> M3 ; Z2 = -0.25*T2@y + 0.75*T2 -> M4  (same step)
    mm_body<256, false>(M1, M2, nullptr, M3, nullptr, 0.5f, 0.0f, 0.0f, nullptr,
                        b, ti, tj, t, As, Bs, red, &s_alpha);
    __syncthreads();   // s_alpha/LDS WAR guard between back-to-back bodies
    mm_body<256, false>(M2, M0, M2, M4, nullptr, -0.25f, 0.75f, 0.0f, nullptr,
                        b, ti, tj, t, As, Bs, red, &s_alpha);
    arrive(cb + 3); waitall(cb + 3);
    // T3 = -Z2@Y2 + 3I                                 -> M1
    mm_body<256, false>(M4, M3, nullptr, M1, nullptr, -1.0f, 0.0f, 3.0f, nullptr,
                        b, ti, tj, t, As, Bs, red, &s_alpha);
    arrive(cb + 4); waitall(cb + 4);
    // Y3 = 0.5*Y2@T3  (+ Frobenius norm^2 partials)    -> M2
    mm_body<256, true>(M3, M1, nullptr, M2, nullptr, 0.5f, 0.0f, 0.0f, nrmp,
                       b, ti, tj, t, As, Bs, red, &s_alpha);
}

// ---------------------------------------------------------------------------
// Kernel 3: projection u[b,e] = sum_k flat[b,k] * W[e,k]. W read ONCE as f32.
// Split-K grid (64,8); block K-chunk 1024 (4 waves x 256), cross-wave LDS
// reduce -> upart[64][64][512].  (round-9 proven)
// ---------------------------------------------------------------------------
__global__ __launch_bounds__(256) void k_proj(const __hip_bfloat16* __restrict__ flat,
                                              const float* __restrict__ W,
                                              float* __restrict__ upart)
{
    __shared__ float racc[2][64][65];
    const int ks = blockIdx.x, et = blockIdx.y;
    const int tid = threadIdx.x, wv = tid >> 6, l = tid & 63;
    const int lr = l & 15, lg = l >> 4;
    const int kbase = ks * 1024 + wv * 256;

    f32x4 acc[4][4];
    #pragma unroll
    for (int i = 0; i < 4; i++)
        #pragma unroll
        for (int j = 0; j < 4; j++)
            #pragma unroll
            for (int r = 0; r < 4; r++) acc[i][j][r] = 0.0f;

    for (int kk = 0; kk < 256; kk += 32) {
        const int k = kbase + kk + lg * 8;
        short8_t af[4];
        #pragma unroll
        for (int i = 0; i < 4; i++)
            af[i] = *reinterpret_cast<const short8_t*>(flat + (size_t)(i * 16 + lr) * CC + k);
        short8_t bfr[4];
        #pragma unroll
        for (int j = 0; j < 4; j++) {
            const f32x4* wp = reinterpret_cast<const f32x4*>(W + (size_t)(et * 64 + j * 16 + lr) * CC + k);
            const f32x4 w0 = wp[0], w1 = wp[1];
            short8_t s;
            s[0] = f2bf(w0[0]); s[1] = f2bf(w0[1]); s[2] = f2bf(w0[2]); s[3] = f2bf(w0[3]);
            s[4] = f2bf(w1[0]); s[5] = f2bf(w1[1]); s[6] = f2bf(w1[2]); s[7] = f2bf(w1[3]);
            bfr[j] = s;
        }
        #pragma unroll
        for (int i = 0; i < 4; i++)
            #pragma unroll
            for (int j = 0; j < 4; j++)
                acc[i][j] = __builtin_amdgcn_mfma_f32_16x16x32_bf16(af[i], bfr[j], acc[i][j], 0, 0, 0);
    }

    if (wv >= 2) {
        #pragma unroll
        for (int i = 0; i < 4; i++)
            #pragma unroll
            for (int j = 0; j < 4; j++)
                #pragma unroll
                for (int r = 0; r < 4; r++)
                    racc[wv - 2][i * 16 + lg * 4 + r][j * 16 + lr] = acc[i][j][r];
    }
    __syncthreads();
    if (wv < 2) {
        #pragma unroll
        for (int i = 0; i < 4; i++)
            #pragma unroll
            for (int j = 0; j < 4; j++)
                #pragma unroll
                for (int r = 0; r < 4; r++)
                    racc[wv][i * 16 + lg * 4 + r][j * 16 + lr] += acc[i][j][r];
    }
    __syncthreads();
    float* ub = upart + (size_t)ks * (64 * EDIM);
    #pragma unroll
    for (int q = 0; q < 16; q++) {
        const int idx = q * 256 + tid;
        const int x = idx >> 6, y = idx & 63;
        ub[(size_t)x * EDIM + et * 64 + y] = racc[0][x][y] + racc[1][x][y];
    }
}

// ---------------------------------------------------------------------------
// Kernel 4: reduce 64 K-partials, 1/||Y3||_F, +bias, BN, final L2 norm.
// ---------------------------------------------------------------------------
__global__ __launch_bounds__(256) void k_fin(const float* __restrict__ upart,
                                             const float* __restrict__ nrmp,
                                             const float* __restrict__ bias,
                                             const float* __restrict__ gma,
                                             const float* __restrict__ bta,
                                             const float* __restrict__ mu,
                                             const float* __restrict__ var,
                                             float* __restrict__ out)
{
    __shared__ float wsum[4];
    const int bb = blockIdx.x;
    const int tid = threadIdx.x, wv = tid >> 6, l = tid & 63;
    const int e0 = tid, e1 = tid + 256;
    float u0 = 0.0f, u1 = 0.0f;
    for (int p = 0; p < 64; ++p) {
        const float* up = upart + ((size_t)p * 64 + bb) * EDIM;
        u0 += up[e0]; u1 += up[e1];
    }
    float fro = 0.0f;
    #pragma unroll
    for (int q = 0; q < NTRI; ++q) fro += nrmp[bb * NTRI + q];
    const float s = 1.0f / fmaxf(sqrtf(fro), 1e-12f);
    const float emb0 = s * u0 + bias[e0];
    const float emb1 = s * u1 + bias[e1];
    const float v0 = (emb0 - mu[e0]) * rsqrtf(var[e0] + 1e-5f) * gma[e0] + bta[e0];
    const float v1 = (emb1 - mu[e1]) * rsqrtf(var[e1] + 1e-5f) * gma[e1] + bta[e1];
    float sq = v0 * v0 + v1 * v1;
    #pragma unroll
    for (int o = 32; o >= 1; o >>= 1) sq += __shfl_xor(sq, o, 64);
    if (l == 0) wsum[wv] = sq;
    __syncthreads();
    const float tot = wsum[0] + wsum[1] + wsum[2] + wsum[3];
    const float rn = 1.0f / fmaxf(sqrtf(tot), 1e-12f);
    out[(size_t)bb * EDIM + e0] = v0 * rn;
    out[(size_t)bb * EDIM + e1] = v1 * rn;
}

// ---------------------------------------------------------------------------
extern "C" void kernel_launch(void* const* d_in, const int* in_sizes, int n_in,
                              void* d_out, int out_size, void* d_ws, size_t ws_size,
                              hipStream_t stream)
{
    const float* feat = (const float*)d_in[0];
    const float* W    = (const float*)d_in[1];
    const float* bias = (const float*)d_in[2];
    const float* gma  = (const float*)d_in[3];
    const float* bta  = (const float*)d_in[4];
    const float* mu   = (const float*)d_in[5];
    const float* var  = (const float*)d_in[6];
    float* out = (float*)d_out;

    char* ws = (char*)d_ws;
    constexpr size_t XCB_BYTES = (size_t)BATCH * CDIM * MP * 2;   //  7,340,032
    constexpr size_t MATB      = (size_t)BATCH * CC * 2;          //  8,388,608
    constexpr size_t OFF_ROWSQ = 8192;
    constexpr size_t OFF_XCB   = OFF_ROWSQ + (size_t)BATCH * CDIM * 4;   // +64KB
    constexpr size_t OFF_M     = OFF_XCB + XCB_BYTES;
    constexpr size_t OFF_UP    = OFF_M + 5 * MATB;
    constexpr size_t NEEDED    = OFF_UP + (size_t)64 * 64 * EDIM * 4;  // ~55 MB
    if (ws_size < NEEDED) return;

    unsigned int* cnt = (unsigned int*)(ws + 0);   // 320 u32
    float* nrmp  = (float*)(ws + 2048);            // 640 floats
    float* rowsq = (float*)(ws + OFF_ROWSQ);       // 16384 floats
    __hip_bfloat16* xcb = (__hip_bfloat16*)(ws + OFF_XCB);
    __hip_bfloat16* M0  = (__hip_bfloat16*)(ws + OFF_M + 0 * MATB);
    __hip_bfloat16* M1  = (__hip_bfloat16*)(ws + OFF_M + 1 * MATB);
    __hip_bfloat16* M2  = (__hip_bfloat16*)(ws + OFF_M + 2 * MATB);
    __hip_bfloat16* M3  = (__hip_bfloat16*)(ws + OFF_M + 3 * MATB);
    __hip_bfloat16* M4  = (__hip_bfloat16*)(ws + OFF_M + 4 * MATB);
    float* upart = (float*)(ws + OFF_UP);

    k_center<<<dim3(4096), dim3(256), 0, stream>>>(feat, xcb, rowsq, cnt);
    k_chain <<<dim3(NMM),  dim3(256), 0, stream>>>(xcb, rowsq, M0, M1, M2, M3, M4,
                                                   nrmp, cnt);
    k_proj  <<<dim3(64, 8), dim3(256), 0, stream>>>(M2, W, upart);
    k_fin   <<<dim3(64),    dim3(256), 0, stream>>>(upart, nrmp, bias, gma, bta,
                                                    mu, var, out);
}

// Round 15
// 123.383 us; speedup vs baseline: 6.4248x; 6.4248x over previous
//
#include <hip/hip_runtime.h>
#include <hip/hip_bf16.h>

#define BATCH 64
#define CDIM  256
#define MHW   196
#define MP    224      // padded K for covariance (multiple of 32)
#define EDIM  512
#define CC    65536    // CDIM*CDIM
#define NTRI  10       // upper-triangle 64x64 tiles of a 256x256 matrix
#define NMM   (BATCH * NTRI)   // 640 mm blocks per step
#define KSP   128      // projection K-splits (K-chunk 512 each)

typedef __attribute__((ext_vector_type(8))) short short8_t;   // 8 x bf16 MFMA frag
typedef __attribute__((ext_vector_type(4))) float f32x4;
typedef __attribute__((ext_vector_type(4))) unsigned int u32x4;

static __device__ __forceinline__ short f2bf(float f) {
    __hip_bfloat16 h = __float2bfloat16(f);
    return (short)__builtin_bit_cast(unsigned short, h);
}

struct MMOp {
    const __hip_bfloat16* A;
    const __hip_bfloat16* B;
    const __hip_bfloat16* D;
    __hip_bfloat16*       out;
    const float*          alpha_ptr;   // mode!=0: rowsq base, a = alpha_c / sum256
    int                   alpha_mode;
    float                 alpha_c, beta, gamma;
    float*                nrm;
};

// ---------------------------------------------------------------------------
// Kernel 1: per-(b,c) row centering + bf16 cast (pad to MP) + rowsq.
// XCD swizzle: blockIdx = r4*64 + b -> XCD(b%8) owns batch b's rows (round-9
// win: matches the mm kernels' placement so cov reads hit the local L2).
// ---------------------------------------------------------------------------
__global__ __launch_bounds__(256) void k_center(const float* __restrict__ feat,
                                                __hip_bfloat16* __restrict__ xcb,
                                                float* __restrict__ rowsq)
{
    const int b  = blockIdx.x & 63;
    const int r4 = blockIdx.x >> 6;
    const int row = b * 256 + r4 * 4 + (threadIdx.x >> 6);
    const int l = threadIdx.x & 63;
    const float* src = feat + (size_t)row * MHW;
    float v0 = src[l];
    float v1 = src[l + 64];
    float v2 = src[l + 128];
    float v3 = (l + 192 < MHW) ? src[l + 192] : 0.0f;
    float s = v0 + v1 + v2 + v3;
    #pragma unroll
    for (int o = 32; o >= 1; o >>= 1) s += __shfl_xor(s, o, 64);
    const float mean = s * (1.0f / MHW);
    v0 -= mean; v1 -= mean; v2 -= mean;
    v3 = (l + 192 < MHW) ? (v3 - mean) : 0.0f;
    float sq = v0*v0 + v1*v1 + v2*v2 + v3*v3;
    #pragma unroll
    for (int o = 32; o >= 1; o >>= 1) sq += __shfl_xor(sq, o, 64);
    if (l == 0) rowsq[row] = sq;
    __hip_bfloat16* dst = xcb + (size_t)row * MP;
    dst[l]       = __float2bfloat16(v0);
    dst[l + 64]  = __float2bfloat16(v1);
    dst[l + 128] = __float2bfloat16(v2);
    if (l + 192 < MP) dst[l + 192] = __float2bfloat16(v3);   // includes zero pad
}

// ---------------------------------------------------------------------------
// Kernel 2: batched symmetric matmul, 64x64 upper-triangle tiles (round-9
// proven shape — r10/r11/r12/r13 alternatives all lost to it).
// out = a*(A@B) + beta*D + gamma*I; B stored exactly symmetric (mirror
// writes) so row-reads give B^T columns.
// XCD swizzle: blockIdx.x = t*64 + b -> all 10 tiles of batch b land on
// XCD b%8 in EVERY launch; inter-step matrices stay in the local L2.
// ---------------------------------------------------------------------------
template<int KT, bool NORM>
__global__ __launch_bounds__(256) void k_mm(MMOp op0, MMOp op1)
{
    const MMOp op = (blockIdx.y == 0) ? op0 : op1;

    __shared__ __hip_bfloat16 As[64][72];   // pad +8: <=2-way bank alias (free)
    __shared__ __hip_bfloat16 Bs[64][72];
    __shared__ float red[4];
    __shared__ float s_alpha;

    const int b = blockIdx.x & 63;
    const int t = blockIdx.x >> 6;
    int ti, tj;
    if (t < 4)      { ti = 0; tj = t; }
    else if (t < 7) { ti = 1; tj = t - 3; }
    else if (t < 9) { ti = 2; tj = t - 5; }
    else            { ti = 3; tj = 3; }

    const int tid = threadIdx.x;
    const int wv = tid >> 6, l = tid & 63;
    const int wr = wv >> 1, wc = wv & 1;
    const int lr = l & 15,  lg = l >> 4;

    if (op.alpha_mode) {
        float v = op.alpha_ptr[b * 256 + tid];
        #pragma unroll
        for (int o = 32; o >= 1; o >>= 1) v += __shfl_xor(v, o, 64);
        if (l == 0) red[wv] = v;
        __syncthreads();
        if (tid == 0) s_alpha = op.alpha_c / (red[0] + red[1] + red[2] + red[3]);
    } else if (tid == 0) {
        s_alpha = op.alpha_c;
    }

    const __hip_bfloat16* Ab = op.A + (size_t)b * (CDIM * KT) + (size_t)ti * 64 * KT;
    const __hip_bfloat16* Bb = op.B + (size_t)b * (CDIM * KT) + (size_t)tj * 64 * KT;

    f32x4 acc[2][2];
    #pragma unroll
    for (int i = 0; i < 2; i++)
        #pragma unroll
        for (int j = 0; j < 2; j++)
            #pragma unroll
            for (int r = 0; r < 4; r++) acc[i][j][r] = 0.0f;

    #pragma unroll
    for (int k0 = 0; k0 < KT; k0 += 64) {
        const int kw   = (KT - k0 >= 64) ? 64 : (KT - k0);   // 64 or 32
        const int segs = kw >> 3;                            // 8 or 4
        __syncthreads();
        for (int u = tid; u < 64 * segs; u += 256) {
            const int row = u / segs;
            const int seg = u - row * segs;
            *reinterpret_cast<u32x4*>(&As[row][seg * 8]) =
                *reinterpret_cast<const u32x4*>(Ab + (size_t)row * KT + k0 + seg * 8);
            *reinterpret_cast<u32x4*>(&Bs[row][seg * 8]) =
                *reinterpret_cast<const u32x4*>(Bb + (size_t)row * KT + k0 + seg * 8);
        }
        __syncthreads();
        const int nks = kw >> 5;   // 2 or 1
        for (int ks = 0; ks < nks; ks++) {
            short8_t af[2], bfr[2];
            #pragma unroll
            for (int i = 0; i < 2; i++)
                af[i] = *reinterpret_cast<const short8_t*>(&As[wr * 32 + i * 16 + lr][ks * 32 + lg * 8]);
            #pragma unroll
            for (int j = 0; j < 2; j++)
                bfr[j] = *reinterpret_cast<const short8_t*>(&Bs[wc * 32 + j * 16 + lr][ks * 32 + lg * 8]);
            #pragma unroll
            for (int i = 0; i < 2; i++)
                #pragma unroll
                for (int j = 0; j < 2; j++)
                    acc[i][j] = __builtin_amdgcn_mfma_f32_16x16x32_bf16(af[i], bfr[j], acc[i][j], 0, 0, 0);
        }
    }

    const float a = s_alpha;
    __hip_bfloat16* ob = op.out + (size_t)b * CC;
    const __hip_bfloat16* Db = op.D ? (op.D + (size_t)b * CC) : nullptr;
    float ns = 0.0f;
    #pragma unroll
    for (int i = 0; i < 2; i++) {
        #pragma unroll
        for (int j = 0; j < 2; j++) {
            #pragma unroll
            for (int r = 0; r < 4; r++) {
                const int grow = ti * 64 + wr * 32 + i * 16 + lg * 4 + r;
                const int gcol = tj * 64 + wc * 32 + j * 16 + lr;
                float v = a * acc[i][j][r];
                if (Db) v += op.beta * __bfloat162float(Db[grow * 256 + gcol]);
                if (grow == gcol) v += op.gamma;
                const __hip_bfloat16 hv = __float2bfloat16(v);
                ob[grow * 256 + gcol] = hv;
                if (ti != tj) ob[gcol * 256 + grow] = hv;   // exact-symmetry mirror
                if (NORM) {
                    const float fv = __bfloat162float(hv);
                    ns += ((ti != tj) ? 2.0f : 1.0f) * fv * fv;
                }
            }
        }
    }
    if constexpr (NORM) {
        #pragma unroll
        for (int o = 32; o >= 1; o >>= 1) ns += __shfl_xor(ns, o, 64);
        __syncthreads();
        if (l == 0) red[wv] = ns;
        __syncthreads();
        if (tid == 0) op.nrm[b * NTRI + t] = red[0] + red[1] + red[2] + red[3];
    }
}

// ---------------------------------------------------------------------------
// Kernel 3: projection u[b,e] = sum_k flat[b,k] * W[e,k]. W read ONCE as f32
// (round-8 proved pre-converting costs 201MB extra traffic, never hidden).
// Split-K grid (128,8) — doubled from round 9's (64,8): 4 blocks/CU resident
// -> deeper HBM load pipeline on the 134MB W stream. Block K-chunk 512
// (4 waves x 128), cross-wave LDS reduce -> upart[128][64][512].
// ---------------------------------------------------------------------------
__global__ __launch_bounds__(256) void k_proj(const __hip_bfloat16* __restrict__ flat,
                                              const float* __restrict__ W,
                                              float* __restrict__ upart)
{
    __shared__ float racc[2][64][65];
    const int ks = blockIdx.x, et = blockIdx.y;
    const int tid = threadIdx.x, wv = tid >> 6, l = tid & 63;
    const int lr = l & 15, lg = l >> 4;
    const int kbase = ks * 512 + wv * 128;

    f32x4 acc[4][4];
    #pragma unroll
    for (int i = 0; i < 4; i++)
        #pragma unroll
        for (int j = 0; j < 4; j++)
            #pragma unroll
            for (int r = 0; r < 4; r++) acc[i][j][r] = 0.0f;

    #pragma unroll
    for (int kk = 0; kk < 128; kk += 32) {
        const int k = kbase + kk + lg * 8;
        short8_t af[4];
        #pragma unroll
        for (int i = 0; i < 4; i++)
            af[i] = *reinterpret_cast<const short8_t*>(flat + (size_t)(i * 16 + lr) * CC + k);
        short8_t bfr[4];
        #pragma unroll
        for (int j = 0; j < 4; j++) {
            const f32x4* wp = reinterpret_cast<const f32x4*>(W + (size_t)(et * 64 + j * 16 + lr) * CC + k);
            const f32x4 w0 = wp[0], w1 = wp[1];
            short8_t s;
            s[0] = f2bf(w0[0]); s[1] = f2bf(w0[1]); s[2] = f2bf(w0[2]); s[3] = f2bf(w0[3]);
            s[4] = f2bf(w1[0]); s[5] = f2bf(w1[1]); s[6] = f2bf(w1[2]); s[7] = f2bf(w1[3]);
            bfr[j] = s;
        }
        #pragma unroll
        for (int i = 0; i < 4; i++)
            #pragma unroll
            for (int j = 0; j < 4; j++)
                acc[i][j] = __builtin_amdgcn_mfma_f32_16x16x32_bf16(af[i], bfr[j], acc[i][j], 0, 0, 0);
    }

    if (wv >= 2) {
        #pragma unroll
        for (int i = 0; i < 4; i++)
            #pragma unroll
            for (int j = 0; j < 4; j++)
                #pragma unroll
                for (int r = 0; r < 4; r++)
                    racc[wv - 2][i * 16 + lg * 4 + r][j * 16 + lr] = acc[i][j][r];
    }
    __syncthreads();
    if (wv < 2) {
        #pragma unroll
        for (int i = 0; i < 4; i++)
            #pragma unroll
            for (int j = 0; j < 4; j++)
                #pragma unroll
                for (int r = 0; r < 4; r++)
                    racc[wv][i * 16 + lg * 4 + r][j * 16 + lr] += acc[i][j][r];
    }
    __syncthreads();
    float* ub = upart + (size_t)ks * (64 * EDIM);
    #pragma unroll
    for (int q = 0; q < 16; q++) {
        const int idx = q * 256 + tid;
        const int x = idx >> 6, y = idx & 63;
        ub[(size_t)x * EDIM + et * 64 + y] = racc[0][x][y] + racc[1][x][y];
    }
}

// ---------------------------------------------------------------------------
// Kernel 4: reduce 128 K-partials, 1/||Y3||_F, +bias, BN, final L2 norm.
// ---------------------------------------------------------------------------
__global__ __launch_bounds__(256) void k_fin(const float* __restrict__ upart,
                                             const float* __restrict__ nrmp,
                                             const float* __restrict__ bias,
                                             const float* __restrict__ gma,
                                             const float* __restrict__ bta,
                                             const float* __restrict__ mu,
                                             const float* __restrict__ var,
                                             float* __restrict__ out)
{
    __shared__ float wsum[4];
    const int bb = blockIdx.x;
    const int tid = threadIdx.x, wv = tid >> 6, l = tid & 63;
    const int e0 = tid, e1 = tid + 256;
    float u0 = 0.0f, u1 = 0.0f;
    for (int p = 0; p < KSP; ++p) {
        const float* up = upart + ((size_t)p * 64 + bb) * EDIM;
        u0 += up[e0]; u1 += up[e1];
    }
    float fro = 0.0f;
    #pragma unroll
    for (int q = 0; q < NTRI; ++q) fro += nrmp[bb * NTRI + q];
    const float s = 1.0f / fmaxf(sqrtf(fro), 1e-12f);
    const float emb0 = s * u0 + bias[e0];
    const float emb1 = s * u1 + bias[e1];
    const float v0 = (emb0 - mu[e0]) * rsqrtf(var[e0] + 1e-5f) * gma[e0] + bta[e0];
    const float v1 = (emb1 - mu[e1]) * rsqrtf(var[e1] + 1e-5f) * gma[e1] + bta[e1];
    float sq = v0 * v0 + v1 * v1;
    #pragma unroll
    for (int o = 32; o >= 1; o >>= 1) sq += __shfl_xor(sq, o, 64);
    if (l == 0) wsum[wv] = sq;
    __syncthreads();
    const float tot = wsum[0] + wsum[1] + wsum[2] + wsum[3];
    const float rn = 1.0f / fmaxf(sqrtf(tot), 1e-12f);
    out[(size_t)bb * EDIM + e0] = v0 * rn;
    out[(size_t)bb * EDIM + e1] = v1 * rn;
}

// ---------------------------------------------------------------------------
extern "C" void kernel_launch(void* const* d_in, const int* in_sizes, int n_in,
                              void* d_out, int out_size, void* d_ws, size_t ws_size,
                              hipStream_t stream)
{
    const float* feat = (const float*)d_in[0];
    const float* W    = (const float*)d_in[1];
    const float* bias = (const float*)d_in[2];
    const float* gma  = (const float*)d_in[3];
    const float* bta  = (const float*)d_in[4];
    const float* mu   = (const float*)d_in[5];
    const float* var  = (const float*)d_in[6];
    float* out = (float*)d_out;

    char* ws = (char*)d_ws;
    constexpr size_t XCB_BYTES = (size_t)BATCH * CDIM * MP * 2;   //  7,340,032
    constexpr size_t MATB      = (size_t)BATCH * CC * 2;          //  8,388,608
    constexpr size_t OFF_ROWSQ = 4096;
    constexpr size_t OFF_XCB   = OFF_ROWSQ + (size_t)BATCH * CDIM * 4;
    constexpr size_t OFF_M     = OFF_XCB + XCB_BYTES;
    constexpr size_t OFF_UP    = OFF_M + 5 * MATB;
    constexpr size_t NEEDED    = OFF_UP + (size_t)KSP * 64 * EDIM * 4;  // ~74 MB
    if (ws_size < NEEDED) return;

    float* nrmp  = (float*)(ws + 1024);          // 640 floats
    float* rowsq = (float*)(ws + OFF_ROWSQ);     // 16384 floats
    __hip_bfloat16* xcb = (__hip_bfloat16*)(ws + OFF_XCB);
    __hip_bfloat16* M0  = (__hip_bfloat16*)(ws + OFF_M + 0 * MATB);
    __hip_bfloat16* M1  = (__hip_bfloat16*)(ws + OFF_M + 1 * MATB);
    __hip_bfloat16* M2  = (__hip_bfloat16*)(ws + OFF_M + 2 * MATB);
    __hip_bfloat16* M3  = (__hip_bfloat16*)(ws + OFF_M + 3 * MATB);
    __hip_bfloat16* M4  = (__hip_bfloat16*)(ws + OFF_M + 4 * MATB);
    float* upart = (float*)(ws + OFF_UP);

    k_center<<<dim3(4096), 256, 0, stream>>>(feat, xcb, rowsq);

    const dim3 g1(NMM, 1), g2(NMM, 2), blk(256);
    MMOp nop = {};

    // y  = (1/tr) * xc @ xc^T                          -> M0
    MMOp cov = {xcb, xcb, nullptr, M0, rowsq, 1, 1.0f, 0.0f, 0.0f, nullptr};
    k_mm<MP, false><<<g1, blk, 0, stream>>>(cov, nop);
    // Y1 = -0.5*y@y + 1.5*y                            -> M1
    MMOp y1 = {M0, M0, M0, M1, nullptr, 0, -0.5f, 1.5f, 0.0f, nullptr};
    k_mm<256, false><<<g1, blk, 0, stream>>>(y1, nop);
    // T2 = 0.5*y@Y1 - 1.5*Y1 + 3I                      -> M2
    MMOp t2 = {M0, M1, M1, M2, nullptr, 0, 0.5f, -1.5f, 3.0f, nullptr};
    k_mm<256, false><<<g1, blk, 0, stream>>>(t2, nop);
    // Y2 = 0.5*Y1@T2 -> M3   ||   Z2 = -0.25*T2@y + 0.75*T2 -> M4   (merged)
    MMOp y2 = {M1, M2, nullptr, M3, nullptr, 0, 0.5f, 0.0f, 0.0f, nullptr};
    MMOp z2 = {M2, M0, M2, M4, nullptr, 0, -0.25f, 0.75f, 0.0f, nullptr};
    k_mm<256, false><<<g2, blk, 0, stream>>>(y2, z2);
    // T3 = -Z2@Y2 + 3I                                 -> M1
    MMOp t3 = {M4, M3, nullptr, M1, nullptr, 0, -1.0f, 0.0f, 3.0f, nullptr};
    k_mm<256, false><<<g1, blk, 0, stream>>>(t3, nop);
    // Y3 = 0.5*Y2@T3  (+ Frobenius norm^2 partials)    -> M2
    MMOp y3 = {M3, M1, nullptr, M2, nullptr, 0, 0.5f, 0.0f, 0.0f, nrmp};
    k_mm<256, true ><<<g1, blk, 0, stream>>>(y3, nop);

    k_proj<<<dim3(KSP, 8), blk, 0, stream>>>(M2, W, upart);
    k_fin<<<dim3(64), blk, 0, stream>>>(upart, nrmp, bias, gma, bta, mu, var, out);
}

// Round 16
// 121.341 us; speedup vs baseline: 6.5329x; 1.0168x over previous
//
#include <hip/hip_runtime.h>
#include <hip/hip_bf16.h>

#define BATCH 64
#define CDIM  256
#define MHW   196
#define MP    224      // padded K for covariance (multiple of 32)
#define EDIM  512
#define CC    65536    // CDIM*CDIM
#define NTRI  10       // upper-triangle 64x64 tiles of a 256x256 matrix
#define NMM   (BATCH * NTRI)   // 640 mm blocks per step

typedef __attribute__((ext_vector_type(8))) short short8_t;   // 8 x bf16 MFMA frag
typedef __attribute__((ext_vector_type(4))) float f32x4;
typedef __attribute__((ext_vector_type(4))) unsigned int u32x4;

static __device__ __forceinline__ short f2bf(float f) {
    __hip_bfloat16 h = __float2bfloat16(f);
    return (short)__builtin_bit_cast(unsigned short, h);
}

struct MMOp {
    const __hip_bfloat16* A;
    const __hip_bfloat16* B;
    const __hip_bfloat16* D;
    __hip_bfloat16*       out;
    const float*          alpha_ptr;   // mode!=0: rowsq base, a = alpha_c / sum256
    int                   alpha_mode;
    float                 alpha_c, beta, gamma;
    float*                nrm;
};

// ---------------------------------------------------------------------------
// Kernel 1: per-(b,c) row centering + bf16 cast (pad to MP) + rowsq.
// XCD swizzle: blockIdx = r4*64 + b -> XCD(b%8) owns batch b's rows (round-9
// win: matches the mm kernels' placement so cov reads hit the local L2).
// ---------------------------------------------------------------------------
__global__ __launch_bounds__(256) void k_center(const float* __restrict__ feat,
                                                __hip_bfloat16* __restrict__ xcb,
                                                float* __restrict__ rowsq)
{
    const int b  = blockIdx.x & 63;
    const int r4 = blockIdx.x >> 6;
    const int row = b * 256 + r4 * 4 + (threadIdx.x >> 6);
    const int l = threadIdx.x & 63;
    const float* src = feat + (size_t)row * MHW;
    float v0 = src[l];
    float v1 = src[l + 64];
    float v2 = src[l + 128];
    float v3 = (l + 192 < MHW) ? src[l + 192] : 0.0f;
    float s = v0 + v1 + v2 + v3;
    #pragma unroll
    for (int o = 32; o >= 1; o >>= 1) s += __shfl_xor(s, o, 64);
    const float mean = s * (1.0f / MHW);
    v0 -= mean; v1 -= mean; v2 -= mean;
    v3 = (l + 192 < MHW) ? (v3 - mean) : 0.0f;
    float sq = v0*v0 + v1*v1 + v2*v2 + v3*v3;
    #pragma unroll
    for (int o = 32; o >= 1; o >>= 1) sq += __shfl_xor(sq, o, 64);
    if (l == 0) rowsq[row] = sq;
    __hip_bfloat16* dst = xcb + (size_t)row * MP;
    dst[l]       = __float2bfloat16(v0);
    dst[l + 64]  = __float2bfloat16(v1);
    dst[l + 128] = __float2bfloat16(v2);
    if (l + 192 < MP) dst[l + 192] = __float2bfloat16(v3);   // includes zero pad
}

// ---------------------------------------------------------------------------
// Kernel 2: batched symmetric matmul, 64x64 upper-triangle tiles (round-9
// proven shape — r10/r11/r12/r13/r15 alternatives all lost to it).
// out = a*(A@B) + beta*D + gamma*I; B stored exactly symmetric (mirror
// writes) so row-reads give B^T columns.
// Diagonal-alias micro-opt: when A==B (cov, Y1) and ti==tj, the B tile is
// byte-identical to the A tile -> stage once, read B-frags from As.
// XCD swizzle: blockIdx.x = t*64 + b -> all 10 tiles of batch b land on
// XCD b%8 in EVERY launch; inter-step matrices stay in the local L2.
// ---------------------------------------------------------------------------
template<int KT, bool NORM>
__global__ __launch_bounds__(256) void k_mm(MMOp op0, MMOp op1)
{
    const MMOp op = (blockIdx.y == 0) ? op0 : op1;

    __shared__ __hip_bfloat16 As[64][72];   // pad +8: <=2-way bank alias (free)
    __shared__ __hip_bfloat16 Bs[64][72];
    __shared__ float red[4];
    __shared__ float s_alpha;

    const int b = blockIdx.x & 63;
    const int t = blockIdx.x >> 6;
    int ti, tj;
    if (t < 4)      { ti = 0; tj = t; }
    else if (t < 7) { ti = 1; tj = t - 3; }
    else if (t < 9) { ti = 2; tj = t - 5; }
    else            { ti = 3; tj = 3; }

    const int tid = threadIdx.x;
    const int wv = tid >> 6, l = tid & 63;
    const int wr = wv >> 1, wc = wv & 1;
    const int lr = l & 15,  lg = l >> 4;

    if (op.alpha_mode) {
        float v = op.alpha_ptr[b * 256 + tid];
        #pragma unroll
        for (int o = 32; o >= 1; o >>= 1) v += __shfl_xor(v, o, 64);
        if (l == 0) red[wv] = v;
        __syncthreads();
        if (tid == 0) s_alpha = op.alpha_c / (red[0] + red[1] + red[2] + red[3]);
    } else if (tid == 0) {
        s_alpha = op.alpha_c;
    }

    const bool alias = (op.A == op.B) && (ti == tj);   // identical stage bytes
    const __hip_bfloat16* Ab = op.A + (size_t)b * (CDIM * KT) + (size_t)ti * 64 * KT;
    const __hip_bfloat16* Bb = op.B + (size_t)b * (CDIM * KT) + (size_t)tj * 64 * KT;
    __hip_bfloat16 (* const Bread)[72] = alias ? As : Bs;

    f32x4 acc[2][2];
    #pragma unroll
    for (int i = 0; i < 2; i++)
        #pragma unroll
        for (int j = 0; j < 2; j++)
            #pragma unroll
            for (int r = 0; r < 4; r++) acc[i][j][r] = 0.0f;

    #pragma unroll
    for (int k0 = 0; k0 < KT; k0 += 64) {
        const int kw   = (KT - k0 >= 64) ? 64 : (KT - k0);   // 64 or 32
        const int segs = kw >> 3;                            // 8 or 4
        __syncthreads();
        for (int u = tid; u < 64 * segs; u += 256) {
            const int row = u / segs;
            const int seg = u - row * segs;
            *reinterpret_cast<u32x4*>(&As[row][seg * 8]) =
                *reinterpret_cast<const u32x4*>(Ab + (size_t)row * KT + k0 + seg * 8);
            if (!alias)
                *reinterpret_cast<u32x4*>(&Bs[row][seg * 8]) =
                    *reinterpret_cast<const u32x4*>(Bb + (size_t)row * KT + k0 + seg * 8);
        }
        __syncthreads();
        const int nks = kw >> 5;   // 2 or 1
        for (int ks = 0; ks < nks; ks++) {
            short8_t af[2], bfr[2];
            #pragma unroll
            for (int i = 0; i < 2; i++)
                af[i] = *reinterpret_cast<const short8_t*>(&As[wr * 32 + i * 16 + lr][ks * 32 + lg * 8]);
            #pragma unroll
            for (int j = 0; j < 2; j++)
                bfr[j] = *reinterpret_cast<const short8_t*>(&Bread[wc * 32 + j * 16 + lr][ks * 32 + lg * 8]);
            #pragma unroll
            for (int i = 0; i < 2; i++)
                #pragma unroll
                for (int j = 0; j < 2; j++)
                    acc[i][j] = __builtin_amdgcn_mfma_f32_16x16x32_bf16(af[i], bfr[j], acc[i][j], 0, 0, 0);
        }
    }

    const float a = s_alpha;
    __hip_bfloat16* ob = op.out + (size_t)b * CC;
    const __hip_bfloat16* Db = op.D ? (op.D + (size_t)b * CC) : nullptr;
    float ns = 0.0f;
    #pragma unroll
    for (int i = 0; i < 2; i++) {
        #pragma unroll
        for (int j = 0; j < 2; j++) {
            #pragma unroll
            for (int r = 0; r < 4; r++) {
                const int grow = ti * 64 + wr * 32 + i * 16 + lg * 4 + r;
                const int gcol = tj * 64 + wc * 32 + j * 16 + lr;
                float v = a * acc[i][j][r];
                if (Db) v += op.beta * __bfloat162float(Db[grow * 256 + gcol]);
                if (grow == gcol) v += op.gamma;
                const __hip_bfloat16 hv = __float2bfloat16(v);
                ob[grow * 256 + gcol] = hv;
                if (ti != tj) ob[gcol * 256 + grow] = hv;   // exact-symmetry mirror
                if (NORM) {
                    const float fv = __bfloat162float(hv);
                    ns += ((ti != tj) ? 2.0f : 1.0f) * fv * fv;
                }
            }
        }
    }
    if constexpr (NORM) {
        #pragma unroll
        for (int o = 32; o >= 1; o >>= 1) ns += __shfl_xor(ns, o, 64);
        __syncthreads();
        if (l == 0) red[wv] = ns;
        __syncthreads();
        if (tid == 0) op.nrm[b * NTRI + t] = red[0] + red[1] + red[2] + red[3];
    }
}

// ---------------------------------------------------------------------------
// Kernel 3: projection u[b,e] = sum_k flat[b,k] * W[e,k]. W read ONCE as f32
// (round-8 proved pre-converting costs 201MB extra traffic, never hidden).
// Split-K grid (64,8) — round-9 proven; (128,8) regressed in r15. Block
// K-chunk 1024 (4 waves x 256), cross-wave LDS reduce -> upart[64][64][512].
// ---------------------------------------------------------------------------
__global__ __launch_bounds__(256) void k_proj(const __hip_bfloat16* __restrict__ flat,
                                              const float* __restrict__ W,
                                              float* __restrict__ upart)
{
    __shared__ float racc[2][64][65];
    const int ks = blockIdx.x, et = blockIdx.y;
    const int tid = threadIdx.x, wv = tid >> 6, l = tid & 63;
    const int lr = l & 15, lg = l >> 4;
    const int kbase = ks * 1024 + wv * 256;

    f32x4 acc[4][4];
    #pragma unroll
    for (int i = 0; i < 4; i++)
        #pragma unroll
        for (int j = 0; j < 4; j++)
            #pragma unroll
            for (int r = 0; r < 4; r++) acc[i][j][r] = 0.0f;

    for (int kk = 0; kk < 256; kk += 32) {
        const int k = kbase + kk + lg * 8;
        short8_t af[4];
        #pragma unroll
        for (int i = 0; i < 4; i++)
            af[i] = *reinterpret_cast<const short8_t*>(flat + (size_t)(i * 16 + lr) * CC + k);
        short8_t bfr[4];
        #pragma unroll
        for (int j = 0; j < 4; j++) {
            const f32x4* wp = reinterpret_cast<const f32x4*>(W + (size_t)(et * 64 + j * 16 + lr) * CC + k);
            const f32x4 w0 = wp[0], w1 = wp[1];
            short8_t s;
            s[0] = f2bf(w0[0]); s[1] = f2bf(w0[1]); s[2] = f2bf(w0[2]); s[3] = f2bf(w0[3]);
            s[4] = f2bf(w1[0]); s[5] = f2bf(w1[1]); s[6] = f2bf(w1[2]); s[7] = f2bf(w1[3]);
            bfr[j] = s;
        }
        #pragma unroll
        for (int i = 0; i < 4; i++)
            #pragma unroll
            for (int j = 0; j < 4; j++)
                acc[i][j] = __builtin_amdgcn_mfma_f32_16x16x32_bf16(af[i], bfr[j], acc[i][j], 0, 0, 0);
    }

    if (wv >= 2) {
        #pragma unroll
        for (int i = 0; i < 4; i++)
            #pragma unroll
            for (int j = 0; j < 4; j++)
                #pragma unroll
                for (int r = 0; r < 4; r++)
                    racc[wv - 2][i * 16 + lg * 4 + r][j * 16 + lr] = acc[i][j][r];
    }
    __syncthreads();
    if (wv < 2) {
        #pragma unroll
        for (int i = 0; i < 4; i++)
            #pragma unroll
            for (int j = 0; j < 4; j++)
                #pragma unroll
                for (int r = 0; r < 4; r++)
                    racc[wv][i * 16 + lg * 4 + r][j * 16 + lr] += acc[i][j][r];
    }
    __syncthreads();
    float* ub = upart + (size_t)ks * (64 * EDIM);
    #pragma unroll
    for (int q = 0; q < 16; q++) {
        const int idx = q * 256 + tid;
        const int x = idx >> 6, y = idx & 63;
        ub[(size_t)x * EDIM + et * 64 + y] = racc[0][x][y] + racc[1][x][y];
    }
}

// ---------------------------------------------------------------------------
// Kernel 4: reduce 64 K-partials, 1/||Y3||_F, +bias, BN, final L2 norm.
// ---------------------------------------------------------------------------
__global__ __launch_bounds__(256) void k_fin(const float* __restrict__ upart,
                                             const float* __restrict__ nrmp,
                                             const float* __restrict__ bias,
                                             const float* __restrict__ gma,
                                             const float* __restrict__ bta,
                                             const float* __restrict__ mu,
                                             const float* __restrict__ var,
                                             float* __restrict__ out)
{
    __shared__ float wsum[4];
    const int bb = blockIdx.x;
    const int tid = threadIdx.x, wv = tid >> 6, l = tid & 63;
    const int e0 = tid, e1 = tid + 256;
    float u0 = 0.0f, u1 = 0.0f;
    for (int p = 0; p < 64; ++p) {
        const float* up = upart + ((size_t)p * 64 + bb) * EDIM;
        u0 += up[e0]; u1 += up[e1];
    }
    float fro = 0.0f;
    #pragma unroll
    for (int q = 0; q < NTRI; ++q) fro += nrmp[bb * NTRI + q];
    const float s = 1.0f / fmaxf(sqrtf(fro), 1e-12f);
    const float emb0 = s * u0 + bias[e0];
    const float emb1 = s * u1 + bias[e1];
    const float v0 = (emb0 - mu[e0]) * rsqrtf(var[e0] + 1e-5f) * gma[e0] + bta[e0];
    const float v1 = (emb1 - mu[e1]) * rsqrtf(var[e1] + 1e-5f) * gma[e1] + bta[e1];
    float sq = v0 * v0 + v1 * v1;
    #pragma unroll
    for (int o = 32; o >= 1; o >>= 1) sq += __shfl_xor(sq, o, 64);
    if (l == 0) wsum[wv] = sq;
    __syncthreads();
    const float tot = wsum[0] + wsum[1] + wsum[2] + wsum[3];
    const float rn = 1.0f / fmaxf(sqrtf(tot), 1e-12f);
    out[(size_t)bb * EDIM + e0] = v0 * rn;
    out[(size_t)bb * EDIM + e1] = v1 * rn;
}

// ---------------------------------------------------------------------------
extern "C" void kernel_launch(void* const* d_in, const int* in_sizes, int n_in,
                              void* d_out, int out_size, void* d_ws, size_t ws_size,
                              hipStream_t stream)
{
    const float* feat = (const float*)d_in[0];
    const float* W    = (const float*)d_in[1];
    const float* bias = (const float*)d_in[2];
    const float* gma  = (const float*)d_in[3];
    const float* bta  = (const float*)d_in[4];
    const float* mu   = (const float*)d_in[5];
    const float* var  = (const float*)d_in[6];
    float* out = (float*)d_out;

    char* ws = (char*)d_ws;
    constexpr size_t XCB_BYTES = (size_t)BATCH * CDIM * MP * 2;   //  7,340,032
    constexpr size_t MATB      = (size_t)BATCH * CC * 2;          //  8,388,608
    constexpr size_t OFF_ROWSQ = 4096;
    constexpr size_t OFF_XCB   = OFF_ROWSQ + (size_t)BATCH * CDIM * 4;
    constexpr size_t OFF_M     = OFF_XCB + XCB_BYTES;
    constexpr size_t OFF_UP    = OFF_M + 5 * MATB;
    constexpr size_t NEEDED    = OFF_UP + (size_t)64 * 64 * EDIM * 4;  // ~66 MB
    if (ws_size < NEEDED) return;

    float* nrmp  = (float*)(ws + 1024);          // 640 floats
    float* rowsq = (float*)(ws + OFF_ROWSQ);     // 16384 floats
    __hip_bfloat16* xcb = (__hip_bfloat16*)(ws + OFF_XCB);
    __hip_bfloat16* M0  = (__hip_bfloat16*)(ws + OFF_M + 0 * MATB);
    __hip_bfloat16* M1  = (__hip_bfloat16*)(ws + OFF_M + 1 * MATB);
    __hip_bfloat16* M2  = (__hip_bfloat16*)(ws + OFF_M + 2 * MATB);
    __hip_bfloat16* M3  = (__hip_bfloat16*)(ws + OFF_M + 3 * MATB);
    __hip_bfloat16* M4  = (__hip_bfloat16*)(ws + OFF_M + 4 * MATB);
    float* upart = (float*)(ws + OFF_UP);

    k_center<<<dim3(4096), 256, 0, stream>>>(feat, xcb, rowsq);

    const dim3 g1(NMM, 1), g2(NMM, 2), blk(256);
    MMOp nop = {};

    // y  = (1/tr) * xc @ xc^T                          -> M0
    MMOp cov = {xcb, xcb, nullptr, M0, rowsq, 1, 1.0f, 0.0f, 0.0f, nullptr};
    k_mm<MP, false><<<g1, blk, 0, stream>>>(cov, nop);
    // Y1 = -0.5*y@y + 1.5*y                            -> M1
    MMOp y1 = {M0, M0, M0, M1, nullptr, 0, -0.5f, 1.5f, 0.0f, nullptr};
    k_mm<256, false><<<g1, blk, 0, stream>>>(y1, nop);
    // T2 = 0.5*y@Y1 - 1.5*Y1 + 3I                      -> M2
    MMOp t2 = {M0, M1, M1, M2, nullptr, 0, 0.5f, -1.5f, 3.0f, nullptr};
    k_mm<256, false><<<g1, blk, 0, stream>>>(t2, nop);
    // Y2 = 0.5*Y1@T2 -> M3   ||   Z2 = -0.25*T2@y + 0.75*T2 -> M4   (merged)
    MMOp y2 = {M1, M2, nullptr, M3, nullptr, 0, 0.5f, 0.0f, 0.0f, nullptr};
    MMOp z2 = {M2, M0, M2, M4, nullptr, 0, -0.25f, 0.75f, 0.0f, nullptr};
    k_mm<256, false><<<g2, blk, 0, stream>>>(y2, z2);
    // T3 = -Z2@Y2 + 3I                                 -> M1
    MMOp t3 = {M4, M3, nullptr, M1, nullptr, 0, -1.0f, 0.0f, 3.0f, nullptr};
    k_mm<256, false><<<g1, blk, 0, stream>>>(t3, nop);
    // Y3 = 0.5*Y2@T3  (+ Frobenius norm^2 partials)    -> M2
    MMOp y3 = {M3, M1, nullptr, M2, nullptr, 0, 0.5f, 0.0f, 0.0f, nrmp};
    k_mm<256, true ><<<g1, blk, 0, stream>>>(y3, nop);

    k_proj<<<dim3(64, 8), blk, 0, stream>>>(M2, W, upart);
    k_fin<<<dim3(64), blk, 0, stream>>>(upart, nrmp, bias, gma, bta, mu, var, out);
}

// Round 17
// 115.092 us; speedup vs baseline: 6.8876x; 1.0543x over previous
//
#include <hip/hip_runtime.h>
#include <hip/hip_bf16.h>

#define BATCH 64
#define CDIM  256
#define MHW   196
#define MP    224      // padded K for covariance (multiple of 32)
#define EDIM  512
#define CC    65536    // CDIM*CDIM
#define NTRI  10       // upper-triangle 64x64 tiles of a 256x256 matrix
#define NMM   (BATCH * NTRI)   // 640 mm blocks per step

typedef __attribute__((ext_vector_type(8))) short short8_t;   // 8 x bf16 MFMA frag
typedef __attribute__((ext_vector_type(4))) float f32x4;
typedef __attribute__((ext_vector_type(4))) unsigned int u32x4;

static __device__ __forceinline__ short f2bf(float f) {
    __hip_bfloat16 h = __float2bfloat16(f);
    return (short)__builtin_bit_cast(unsigned short, h);
}

struct MMOp {
    const __hip_bfloat16* A;
    const __hip_bfloat16* B;
    const __hip_bfloat16* D;
    __hip_bfloat16*       out;
    const float*          alpha_ptr;   // mode!=0: rowsq base, a = alpha_c / sum256
    int                   alpha_mode;
    float                 alpha_c, beta, gamma;
    float*                nrm;
};

// ---------------------------------------------------------------------------
// Kernel 1: per-(b,c) row centering + bf16 cast (pad to MP) + rowsq.
// XCD swizzle: blockIdx = r4*64 + b -> XCD(b%8) owns batch b's xcb rows,
// matching the mm kernels' placement so cov reads hit the local L2.
// ---------------------------------------------------------------------------
__global__ __launch_bounds__(256) void k_center(const float* __restrict__ feat,
                                                __hip_bfloat16* __restrict__ xcb,
                                                float* __restrict__ rowsq)
{
    const int b  = blockIdx.x & 63;
    const int r4 = blockIdx.x >> 6;
    const int row = b * 256 + r4 * 4 + (threadIdx.x >> 6);
    const int l = threadIdx.x & 63;
    const float* src = feat + (size_t)row * MHW;
    float v0 = src[l];
    float v1 = src[l + 64];
    float v2 = src[l + 128];
    float v3 = (l + 192 < MHW) ? src[l + 192] : 0.0f;
    float s = v0 + v1 + v2 + v3;
    #pragma unroll
    for (int o = 32; o >= 1; o >>= 1) s += __shfl_xor(s, o, 64);
    const float mean = s * (1.0f / MHW);
    v0 -= mean; v1 -= mean; v2 -= mean;
    v3 = (l + 192 < MHW) ? (v3 - mean) : 0.0f;
    float sq = v0*v0 + v1*v1 + v2*v2 + v3*v3;
    #pragma unroll
    for (int o = 32; o >= 1; o >>= 1) sq += __shfl_xor(sq, o, 64);
    if (l == 0) rowsq[row] = sq;
    __hip_bfloat16* dst = xcb + (size_t)row * MP;
    dst[l]       = __float2bfloat16(v0);
    dst[l + 64]  = __float2bfloat16(v1);
    dst[l + 128] = __float2bfloat16(v2);
    if (l + 192 < MP) dst[l + 192] = __float2bfloat16(v3);   // includes zero pad
}

// ---------------------------------------------------------------------------
// Kernel 2: batched symmetric matmul, 64x64 upper-triangle tiles.
// out = a*(A@B) + beta*D + gamma*I; B stored exactly symmetric (mirror
// writes) so row-reads give B^T columns.
// XCD swizzle: blockIdx.x = t*64 + b -> all 10 tiles of batch b land on
// XCD b%8 in EVERY launch; inter-step 128KB/batch matrices stay in the
// local 4MB L2 instead of bouncing through L3. (Round-9 proven shape:
// r10 8-wave, r11 reg-prefetch, r12 fused-center, r13/14 flag-chain,
// r15 deeper split-K, r16 diagonal-alias all measured worse.)
// ---------------------------------------------------------------------------
template<int KT, bool NORM>
__global__ __launch_bounds__(256) void k_mm(MMOp op0, MMOp op1)
{
    const MMOp op = (blockIdx.y == 0) ? op0 : op1;

    __shared__ __hip_bfloat16 As[64][72];   // pad +8: <=2-way bank alias (free)
    __shared__ __hip_bfloat16 Bs[64][72];
    __shared__ float red[4];
    __shared__ float s_alpha;

    const int b = blockIdx.x & 63;
    const int t = blockIdx.x >> 6;
    int ti, tj;
    if (t < 4)      { ti = 0; tj = t; }
    else if (t < 7) { ti = 1; tj = t - 3; }
    else if (t < 9) { ti = 2; tj = t - 5; }
    else            { ti = 3; tj = 3; }

    const int tid = threadIdx.x;
    const int wv = tid >> 6, l = tid & 63;
    const int wr = wv >> 1, wc = wv & 1;
    const int lr = l & 15,  lg = l >> 4;

    if (op.alpha_mode) {
        float v = op.alpha_ptr[b * 256 + tid];
        #pragma unroll
        for (int o = 32; o >= 1; o >>= 1) v += __shfl_xor(v, o, 64);
        if (l == 0) red[wv] = v;
        __syncthreads();
        if (tid == 0) s_alpha = op.alpha_c / (red[0] + red[1] + red[2] + red[3]);
    } else if (tid == 0) {
        s_alpha = op.alpha_c;
    }

    const __hip_bfloat16* Ab = op.A + (size_t)b * (CDIM * KT) + (size_t)ti * 64 * KT;
    const __hip_bfloat16* Bb = op.B + (size_t)b * (CDIM * KT) + (size_t)tj * 64 * KT;

    f32x4 acc[2][2];
    #pragma unroll
    for (int i = 0; i < 2; i++)
        #pragma unroll
        for (int j = 0; j < 2; j++)
            #pragma unroll
            for (int r = 0; r < 4; r++) acc[i][j][r] = 0.0f;

    #pragma unroll
    for (int k0 = 0; k0 < KT; k0 += 64) {
        const int kw   = (KT - k0 >= 64) ? 64 : (KT - k0);   // 64 or 32
        const int segs = kw >> 3;                            // 8 or 4
        __syncthreads();
        for (int u = tid; u < 64 * segs; u += 256) {
            const int row = u / segs;
            const int seg = u - row * segs;
            *reinterpret_cast<u32x4*>(&As[row][seg * 8]) =
                *reinterpret_cast<const u32x4*>(Ab + (size_t)row * KT + k0 + seg * 8);
            *reinterpret_cast<u32x4*>(&Bs[row][seg * 8]) =
                *reinterpret_cast<const u32x4*>(Bb + (size_t)row * KT + k0 + seg * 8);
        }
        __syncthreads();
        const int nks = kw >> 5;   // 2 or 1
        for (int ks = 0; ks < nks; ks++) {
            short8_t af[2], bfr[2];
            #pragma unroll
            for (int i = 0; i < 2; i++)
                af[i] = *reinterpret_cast<const short8_t*>(&As[wr * 32 + i * 16 + lr][ks * 32 + lg * 8]);
            #pragma unroll
            for (int j = 0; j < 2; j++)
                bfr[j] = *reinterpret_cast<const short8_t*>(&Bs[wc * 32 + j * 16 + lr][ks * 32 + lg * 8]);
            #pragma unroll
            for (int i = 0; i < 2; i++)
                #pragma unroll
                for (int j = 0; j < 2; j++)
                    acc[i][j] = __builtin_amdgcn_mfma_f32_16x16x32_bf16(af[i], bfr[j], acc[i][j], 0, 0, 0);
        }
    }

    const float a = s_alpha;
    __hip_bfloat16* ob = op.out + (size_t)b * CC;
    const __hip_bfloat16* Db = op.D ? (op.D + (size_t)b * CC) : nullptr;
    float ns = 0.0f;
    #pragma unroll
    for (int i = 0; i < 2; i++) {
        #pragma unroll
        for (int j = 0; j < 2; j++) {
            #pragma unroll
            for (int r = 0; r < 4; r++) {
                const int grow = ti * 64 + wr * 32 + i * 16 + lg * 4 + r;
                const int gcol = tj * 64 + wc * 32 + j * 16 + lr;
                float v = a * acc[i][j][r];
                if (Db) v += op.beta * __bfloat162float(Db[grow * 256 + gcol]);
                if (grow == gcol) v += op.gamma;
                const __hip_bfloat16 hv = __float2bfloat16(v);
                ob[grow * 256 + gcol] = hv;
                if (ti != tj) ob[gcol * 256 + grow] = hv;   // exact-symmetry mirror
                if (NORM) {
                    const float fv = __bfloat162float(hv);
                    ns += ((ti != tj) ? 2.0f : 1.0f) * fv * fv;
                }
            }
        }
    }
    if constexpr (NORM) {
        #pragma unroll
        for (int o = 32; o >= 1; o >>= 1) ns += __shfl_xor(ns, o, 64);
        __syncthreads();
        if (l == 0) red[wv] = ns;
        __syncthreads();
        if (tid == 0) op.nrm[b * NTRI + t] = red[0] + red[1] + red[2] + red[3];
    }
}

// ---------------------------------------------------------------------------
// Kernel 3: projection u[b,e] = sum_k flat[b,k] * W[e,k]. W read ONCE as f32
// (round-8 proved pre-converting costs 201MB extra traffic, never hidden;
// round-15 proved deeper split-K regresses). Split-K grid (64,8); block
// K-chunk 1024 (4 waves x 256), cross-wave LDS reduce -> upart[64][64][512].
// ---------------------------------------------------------------------------
__global__ __launch_bounds__(256) void k_proj(const __hip_bfloat16* __restrict__ flat,
                                              const float* __restrict__ W,
                                              float* __restrict__ upart)
{
    __shared__ float racc[2][64][65];
    const int ks = blockIdx.x, et = blockIdx.y;
    const int tid = threadIdx.x, wv = tid >> 6, l = tid & 63;
    const int lr = l & 15, lg = l >> 4;
    const int kbase = ks * 1024 + wv * 256;

    f32x4 acc[4][4];
    #pragma unroll
    for (int i = 0; i < 4; i++)
        #pragma unroll
        for (int j = 0; j < 4; j++)
            #pragma unroll
            for (int r = 0; r < 4; r++) acc[i][j][r] = 0.0f;

    for (int kk = 0; kk < 256; kk += 32) {
        const int k = kbase + kk + lg * 8;
        short8_t af[4];
        #pragma unroll
        for (int i = 0; i < 4; i++)
            af[i] = *reinterpret_cast<const short8_t*>(flat + (size_t)(i * 16 + lr) * CC + k);
        short8_t bfr[4];
        #pragma unroll
        for (int j = 0; j < 4; j++) {
            const f32x4* wp = reinterpret_cast<const f32x4*>(W + (size_t)(et * 64 + j * 16 + lr) * CC + k);
            const f32x4 w0 = wp[0], w1 = wp[1];
            short8_t s;
            s[0] = f2bf(w0[0]); s[1] = f2bf(w0[1]); s[2] = f2bf(w0[2]); s[3] = f2bf(w0[3]);
            s[4] = f2bf(w1[0]); s[5] = f2bf(w1[1]); s[6] = f2bf(w1[2]); s[7] = f2bf(w1[3]);
            bfr[j] = s;
        }
        #pragma unroll
        for (int i = 0; i < 4; i++)
            #pragma unroll
            for (int j = 0; j < 4; j++)
                acc[i][j] = __builtin_amdgcn_mfma_f32_16x16x32_bf16(af[i], bfr[j], acc[i][j], 0, 0, 0);
    }

    if (wv >= 2) {
        #pragma unroll
        for (int i = 0; i < 4; i++)
            #pragma unroll
            for (int j = 0; j < 4; j++)
                #pragma unroll
                for (int r = 0; r < 4; r++)
                    racc[wv - 2][i * 16 + lg * 4 + r][j * 16 + lr] = acc[i][j][r];
    }
    __syncthreads();
    if (wv < 2) {
        #pragma unroll
        for (int i = 0; i < 4; i++)
            #pragma unroll
            for (int j = 0; j < 4; j++)
                #pragma unroll
                for (int r = 0; r < 4; r++)
                    racc[wv][i * 16 + lg * 4 + r][j * 16 + lr] += acc[i][j][r];
    }
    __syncthreads();
    float* ub = upart + (size_t)ks * (64 * EDIM);
    #pragma unroll
    for (int q = 0; q < 16; q++) {
        const int idx = q * 256 + tid;
        const int x = idx >> 6, y = idx & 63;
        ub[(size_t)x * EDIM + et * 64 + y] = racc[0][x][y] + racc[1][x][y];
    }
}

// ---------------------------------------------------------------------------
// Kernel 4: reduce 64 K-partials, 1/||Y3||_F, +bias, BN, final L2 norm.
// ---------------------------------------------------------------------------
__global__ __launch_bounds__(256) void k_fin(const float* __restrict__ upart,
                                             const float* __restrict__ nrmp,
                                             const float* __restrict__ bias,
                                             const float* __restrict__ gma,
                                             const float* __restrict__ bta,
                                             const float* __restrict__ mu,
                                             const float* __restrict__ var,
                                             float* __restrict__ out)
{
    __shared__ float wsum[4];
    const int bb = blockIdx.x;
    const int tid = threadIdx.x, wv = tid >> 6, l = tid & 63;
    const int e0 = tid, e1 = tid + 256;
    float u0 = 0.0f, u1 = 0.0f;
    for (int p = 0; p < 64; ++p) {
        const float* up = upart + ((size_t)p * 64 + bb) * EDIM;
        u0 += up[e0]; u1 += up[e1];
    }
    float fro = 0.0f;
    #pragma unroll
    for (int q = 0; q < NTRI; ++q) fro += nrmp[bb * NTRI + q];
    const float s = 1.0f / fmaxf(sqrtf(fro), 1e-12f);
    const float emb0 = s * u0 + bias[e0];
    const float emb1 = s * u1 + bias[e1];
    const float v0 = (emb0 - mu[e0]) * rsqrtf(var[e0] + 1e-5f) * gma[e0] + bta[e0];
    const float v1 = (emb1 - mu[e1]) * rsqrtf(var[e1] + 1e-5f) * gma[e1] + bta[e1];
    float sq = v0 * v0 + v1 * v1;
    #pragma unroll
    for (int o = 32; o >= 1; o >>= 1) sq += __shfl_xor(sq, o, 64);
    if (l == 0) wsum[wv] = sq;
    __syncthreads();
    const float tot = wsum[0] + wsum[1] + wsum[2] + wsum[3];
    const float rn = 1.0f / fmaxf(sqrtf(tot), 1e-12f);
    out[(size_t)bb * EDIM + e0] = v0 * rn;
    out[(size_t)bb * EDIM + e1] = v1 * rn;
}

// ---------------------------------------------------------------------------
extern "C" void kernel_launch(void* const* d_in, const int* in_sizes, int n_in,
                              void* d_out, int out_size, void* d_ws, size_t ws_size,
                              hipStream_t stream)
{
    const float* feat = (const float*)d_in[0];
    const float* W    = (const float*)d_in[1];
    const float* bias = (const float*)d_in[2];
    const float* gma  = (const float*)d_in[3];
    const float* bta  = (const float*)d_in[4];
    const float* mu   = (const float*)d_in[5];
    const float* var  = (const float*)d_in[6];
    float* out = (float*)d_out;

    char* ws = (char*)d_ws;
    constexpr size_t XCB_BYTES = (size_t)BATCH * CDIM * MP * 2;   //  7,340,032
    constexpr size_t MATB      = (size_t)BATCH * CC * 2;          //  8,388,608
    constexpr size_t OFF_ROWSQ = 4096;
    constexpr size_t OFF_XCB   = OFF_ROWSQ + (size_t)BATCH * CDIM * 4;
    constexpr size_t OFF_M     = OFF_XCB + XCB_BYTES;
    constexpr size_t OFF_UP    = OFF_M + 5 * MATB;
    constexpr size_t NEEDED    = OFF_UP + (size_t)64 * 64 * EDIM * 4;  // ~66 MB
    if (ws_size < NEEDED) return;

    float* nrmp  = (float*)(ws + 1024);          // 640 floats
    float* rowsq = (float*)(ws + OFF_ROWSQ);     // 16384 floats
    __hip_bfloat16* xcb = (__hip_bfloat16*)(ws + OFF_XCB);
    __hip_bfloat16* M0  = (__hip_bfloat16*)(ws + OFF_M + 0 * MATB);
    __hip_bfloat16* M1  = (__hip_bfloat16*)(ws + OFF_M + 1 * MATB);
    __hip_bfloat16* M2  = (__hip_bfloat16*)(ws + OFF_M + 2 * MATB);
    __hip_bfloat16* M3  = (__hip_bfloat16*)(ws + OFF_M + 3 * MATB);
    __hip_bfloat16* M4  = (__hip_bfloat16*)(ws + OFF_M + 4 * MATB);
    float* upart = (float*)(ws + OFF_UP);

    k_center<<<dim3(4096), 256, 0, stream>>>(feat, xcb, rowsq);

    const dim3 g1(NMM, 1), g2(NMM, 2), blk(256);
    MMOp nop = {};

    // y  = (1/tr) * xc @ xc^T                          -> M0
    MMOp cov = {xcb, xcb, nullptr, M0, rowsq, 1, 1.0f, 0.0f, 0.0f, nullptr};
    k_mm<MP, false><<<g1, blk, 0, stream>>>(cov, nop);
    // Y1 = -0.5*y@y + 1.5*y                            -> M1
    MMOp y1 = {M0, M0, M0, M1, nullptr, 0, -0.5f, 1.5f, 0.0f, nullptr};
    k_mm<256, false><<<g1, blk, 0, stream>>>(y1, nop);
    // T2 = 0.5*y@Y1 - 1.5*Y1 + 3I                      -> M2
    MMOp t2 = {M0, M1, M1, M2, nullptr, 0, 0.5f, -1.5f, 3.0f, nullptr};
    k_mm<256, false><<<g1, blk, 0, stream>>>(t2, nop);
    // Y2 = 0.5*Y1@T2 -> M3   ||   Z2 = -0.25*T2@y + 0.75*T2 -> M4   (merged)
    MMOp y2 = {M1, M2, nullptr, M3, nullptr, 0, 0.5f, 0.0f, 0.0f, nullptr};
    MMOp z2 = {M2, M0, M2, M4, nullptr, 0, -0.25f, 0.75f, 0.0f, nullptr};
    k_mm<256, false><<<g2, blk, 0, stream>>>(y2, z2);
    // T3 = -Z2@Y2 + 3I                                 -> M1
    MMOp t3 = {M4, M3, nullptr, M1, nullptr, 0, -1.0f, 0.0f, 3.0f, nullptr};
    k_mm<256, false><<<g1, blk, 0, stream>>>(t3, nop);
    // Y3 = 0.5*Y2@T3  (+ Frobenius norm^2 partials)    -> M2
    MMOp y3 = {M3, M1, nullptr, M2, nullptr, 0, 0.5f, 0.0f, 0.0f, nrmp};
    k_mm<256, true ><<<g1, blk, 0, stream>>>(y3, nop);

    k_proj<<<dim3(64, 8), blk, 0, stream>>>(M2, W, upart);
    k_fin<<<dim3(64), blk, 0, stream>>>(upart, nrmp, bias, gma, bta, mu, var, out);
}